// Round 7
// baseline (240.561 us; speedup 1.0000x reference)
//
#include <hip/hip_runtime.h>
#include <math.h>

#define NQ  12
#define TPB 256

// ================= compile-time GF(2) machinery =================
// Fixed physical layout (CNOT-folded storage space, validated r1/r3/r6):
// gate on qubit q in layer l pairs x <-> x^v (v = col b of Minv_l, b=11-q),
// role = parity(r & x) (r = row b of M_l), r_j . v_i = delta_ij.
// IN-PLACE passes (validated r6): pass p, thread t owns coset
// addr[z] = B_p t ^ C_p[z]; reads, applies 4 gates, writes back SAME addrs.
// NEW (r7): passes are PAIRED. Pair (2m,2m+1) shares a 10-dim subspace
// S >= span{V_2m u V_2m+1} with B[0..5] of both passes inside S and
// IDENTICAL wave vectors B[6],B[7] outside S -> each wave's pass-(2m+1)
// read set == its own pass-2m write set -> intra-pair transition needs NO
// s_barrier (in-wave LDS RAW is ordered by lgkmcnt). Barriers: 11 -> 5.
// Bank conflict floor (validated r6): B[0..3] residues 1,2,4,8, B[4..5]
// residue 0 -> 4-dwords/bank floor for wave64 b64.

struct GF12 { unsigned row[12]; };

constexpr GF12 gf_id(){ GF12 m{}; for(int i=0;i<12;i++) m.row[i]=1u<<i; return m; }
constexpr GF12 gf_mul(const GF12&A,const GF12&B){
  GF12 r{};
  for(int i=0;i<12;i++){ unsigned acc=0;
    for(int k=0;k<12;k++) if((A.row[i]>>k)&1u) acc ^= B.row[k];
    r.row[i]=acc; }
  return r;
}
constexpr GF12 gf_cnot(int q){ GF12 m=gf_id(); int c=11-q, t=11-((q+1)%12); m.row[t]^=(1u<<c); return m; }

// incremental GF(2) elimination state (cheap: O(n) per candidate test)
struct Red { unsigned arr[12]; int hb[12]; int n; };
constexpr unsigned red_reduce(const Red& R, unsigned y){
  for(int i=0;i<R.n;i++) if((y>>R.hb[i])&1u) y ^= R.arr[i];
  return y;
}
constexpr bool red_add(Red& R, unsigned cand){
  unsigned y = red_reduce(R, cand);
  if(!y) return false;
  int h=0;
  for(int b2=11;b2>=1;b2--) if((y>>b2)&1u){ h=b2; break; }
  R.arr[R.n]=y; R.hb[R.n]=h; R.n++;
  return true;
}

struct Tab4 {
  unsigned B[12][8];     // lane rep basis per pass (float2-index space)
  unsigned C[12][16];    // slot coset offsets per pass
  unsigned M[12][4];     // role masks (8-bit over t) per gate
  unsigned mq[12];       // measurement lane-sign masks (8-bit over t)
  unsigned uq[12];       // measurement WHT index (4-bit over z)
  bool ok;
};

constexpr Tab4 make4(){
  Tab4 T{}; T.ok=true;
  // v/r construction (validated r1/r3/r6)
  GF12 D=gf_id(); for(int q=0;q<12;q++) D=gf_mul(gf_cnot(q),D);
  GF12 Cm=gf_id(); for(int q=11;q>=0;q--) Cm=gf_mul(gf_cnot(q),Cm);
  unsigned V[12][4]{},R[12][4]{},rfin[12]{};
  GF12 Mm=gf_id(), Mi=gf_id();
  for(int l=0;l<4;l++){
    for(int q=0;q<12;q++){
      int b=11-q; unsigned v=0;
      for(int j=0;j<12;j++) v|=((Mi.row[j]>>b)&1u)<<j;
      V[l*3+q/4][q&3]=v; R[l*3+q/4][q&3]=Mm.row[b];
    }
    Mm=gf_mul(D,Mm); Mi=gf_mul(Cm,Mi);
  }
  for(int q=0;q<12;q++) rfin[q]=Mm.row[11-q];

  for(int m=0;m<6;m++){
    const int p0=2*m, p1=p0+1;
    // S = span{V[p0] u V[p1]} extended to 10 dims
    Red S{};
    for(int i=0;i<4;i++){ red_add(S,V[p0][i]); red_add(S,V[p1][i]); }
    for(unsigned x=1; x<4096 && S.n<10; x++) red_add(S,x);
    if(S.n!=10) T.ok=false;
    // shared wave vectors outside S
    unsigned W6=0,W7=0;
    { Red SB=S;
      for(unsigned x=1;x<4096 && !W6;x++) if(red_reduce(SB,x)){ W6=x; red_add(SB,x); }
      for(unsigned x=1;x<4096 && !W7;x++) if(red_reduce(SB,x)){ W7=x; red_add(SB,x); }
      if(!W6||!W7) T.ok=false;
    }
    for(int pi=0; pi<2; pi++){
      const int p = (pi==0)?p0:p1;
      // role identity r_j . v_i = delta_ij
      for(int j=0;j<4;j++) for(int i=0;i<4;i++){
        int par=__builtin_popcount(R[p][j]&V[p][i])&1;
        if(par!=((i==j)?1:0)) T.ok=false;
      }
      Red P{};
      for(int i=0;i<4;i++) if(!red_add(P,V[p][i])) T.ok=false;
      // B[0..3]: in S, indep, residue forced to 1,2,4,8 (fallback: any in S indep)
      for(int k=0;k<4;k++){
        unsigned pick=0;
        for(unsigned hi=0;hi<256 && !pick;hi++){
          unsigned x=(1u<<k)|(hi<<4);
          if(red_reduce(S,x)) continue;      // must lie in S
          if(!red_reduce(P,x)) continue;     // must be independent
          pick=x;
        }
        if(!pick){
          for(unsigned x=1;x<4096 && !pick;x++){
            if(red_reduce(S,x)) continue;
            if(!red_reduce(P,x)) continue;
            pick=x;
          }
        }
        if(!pick){ T.ok=false; pick=1u<<k; }
        red_add(P,pick); T.B[p][k]=pick;
      }
      // B[4..5]: in S, indep, residue 0 (fallback: any in S indep)
      for(int k=4;k<6;k++){
        unsigned pick=0;
        for(unsigned hi=1;hi<256 && !pick;hi++){
          unsigned x=hi<<4;
          if(red_reduce(S,x)) continue;
          if(!red_reduce(P,x)) continue;
          pick=x;
        }
        if(!pick){
          for(unsigned x=1;x<4096 && !pick;x++){
            if(red_reduce(S,x)) continue;
            if(!red_reduce(P,x)) continue;
            pick=x;
          }
        }
        if(!pick){ T.ok=false; pick=16; }
        red_add(P,pick); T.B[p][k]=pick;
      }
      T.B[p][6]=W6; T.B[p][7]=W7;
      if(P.n!=10) T.ok=false;
      { Red F=P;
        if(!red_add(F,W6)) T.ok=false;
        if(!red_add(F,W7)) T.ok=false;
        if(F.n!=12) T.ok=false; }
      // slot offsets + role masks
      for(int z=0;z<16;z++){
        unsigned c=0;
        for(int i=0;i<4;i++) if((z>>i)&1) c^=V[p][i];
        T.C[p][z]=c;
      }
      for(int j=0;j<4;j++){
        unsigned mm=0;
        for(int i=0;i<8;i++) mm|=(unsigned)(__builtin_popcount(R[p][j]&T.B[p][i])&1)<<i;
        T.M[p][j]=mm;
      }
    }
    // pair-coupling invariant: every pass-p1 basis/coset vector lies in
    // span{B[p0][0..5]} + span{V[p0]} (== S) and wave vectors match.
    { Red S0{};
      for(int i=0;i<4;i++) red_add(S0,V[p0][i]);
      for(int i=0;i<6;i++) red_add(S0,T.B[p0][i]);
      if(S0.n!=10) T.ok=false;
      for(int i=0;i<6;i++) if(red_reduce(S0,T.B[p1][i])) T.ok=false;
      for(int i=0;i<4;i++) if(red_reduce(S0,V[p1][i])) T.ok=false;
      if(T.B[p0][6]!=T.B[p1][6] || T.B[p0][7]!=T.B[p1][7]) T.ok=false;
    }
  }
  // measurement: sign_q(x)=parity(rfin_q & x), x = B11 t ^ C11[z]
  for(int q=0;q<12;q++){
    unsigned u=0,mm=0;
    for(int i=0;i<4;i++) u|=(unsigned)(__builtin_popcount(rfin[q]&V[11][i])&1)<<i;
    for(int i=0;i<8;i++) mm|=(unsigned)(__builtin_popcount(rfin[q]&T.B[11][i])&1)<<i;
    T.uq[q]=u; T.mq[q]=mm;
  }
  return T;
}

constexpr Tab4 hT4 = make4();
static_assert(hT4.ok, "GF(2) paired in-place table self-check failed");
__constant__ Tab4 cT4 = hT4;

// register slot n_: re/im inside float4 Q[8].
// param must NOT be named x/y/z/w (macro member-token capture, r2 lesson).
#define SR(n_) (((n_)&1) ? Q[(n_)>>1].z : Q[(n_)>>1].x)
#define SI(n_) (((n_)&1) ? Q[(n_)>>1].w : Q[(n_)>>1].y)

// butterfly with per-lane sign folded into ai/br (validated r1)
#define GATE(MM,JJ) do { \
    const int _lb = pl + 4*(JJ); \
    const unsigned _sg = ((unsigned)(__popc((MM) & (unsigned)t) & 1)) << 31; \
    const float ar = __uint_as_float((unsigned)__builtin_amdgcn_readlane((int)cur, _lb+0)); \
    const float ai = __uint_as_float(((unsigned)__builtin_amdgcn_readlane((int)cur, _lb+1)) ^ _sg); \
    const float br = __uint_as_float(((unsigned)__builtin_amdgcn_readlane((int)cur, _lb+2)) ^ _sg); \
    const float bi = __uint_as_float((unsigned)__builtin_amdgcn_readlane((int)cur, _lb+3)); \
    _Pragma("unroll") \
    for (int s0=0; s0<16; ++s0){ \
      if ((s0 >> (JJ)) & 1) continue; \
      const int s1 = s0 | (1<<(JJ)); \
      const float xr=SR(s0), xi=SI(s0), yr=SR(s1), yi=SI(s1); \
      SR(s0)=fmaf(ar,xr,fmaf(-ai,xi,fmaf(br,yr,-(bi*yi)))); \
      SI(s0)=fmaf(ar,xi,fmaf( ai,xr,fmaf(br,yi,  bi*yr ))); \
      SR(s1)=fmaf(ar,yr,fmaf( ai,yi,fmaf(-br,xr,-(bi*xi)))); \
      SI(s1)=fmaf(ar,yi,fmaf(-ai,yr,fmaf( bi,xr,-(br*xi)))); \
    } \
  } while(0)

__global__ void __launch_bounds__(TPB, 5)
qgen(const float* __restrict__ noise,
     const float* __restrict__ W1, const float* __restrict__ b1,
     const float* __restrict__ W2, const float* __restrict__ b2,
     const float* __restrict__ W3, const float* __restrict__ b3,
     const float* __restrict__ W4, const float* __restrict__ b4,
     float* __restrict__ out)
{
  __shared__ float2 s2[4096];              // exactly 32 KiB -> 5 blocks/CU
  float*  sf = (float*)s2;
  float4* s4 = (float4*)s2;

  const int t = threadIdx.x;
  const int b = blockIdx.x;
  const int lane = t & 63;

  // ---- prologue MLP (scratch aliased into state region; r3/r6-validated) ----
  // gates: floats 0..191 | h: 192..255 | par: 256..399 | noise: 400..411
  if (t < 12) sf[400+t] = noise[b*12+t];
  __syncthreads();
  if (t < 64){
    float a = b1[t];
    #pragma unroll
    for (int k=0;k<12;++k) a = fmaf(sf[400+k], W1[k*64+t], a);
    sf[192+t] = tanhf(a);
  }
  __syncthreads();
  if (t < 144){
    float a = b2[t];
    #pragma unroll 16
    for (int j=0;j<64;++j) a = fmaf(sf[192+j], W2[j*144+t], a);
    sf[256+t] = a;
  }
  __syncthreads();
  if (t < 48){
    float aa = sf[256+3*t+0]*0.5f, bb = sf[256+3*t+1]*0.5f, c = sf[256+3*t+2]*0.5f;
    float sa,ca,sb,cb,sc2,cc;
    __sincosf(aa,&sa,&ca); __sincosf(bb,&sb,&cb); __sincosf(c,&sc2,&cc);
    float A=cb*ca, B=sb*sa, Cc=sb*ca, Dd=cb*sa;
    s4[t] = make_float4(fmaf(cc,A,  sc2*B),  fmaf(cc,B, -sc2*A),
                        fmaf(-cc,Cc,-sc2*Dd), fmaf(sc2,Cc,-cc*Dd));
  }
  __syncthreads();
  // pull 48 gate float4s (192 dwords) into 3 per-lane regs (each wave a copy)
  const unsigned* su = (const unsigned*)s2;
  const unsigned cu0 = su[lane], cu1 = su[64+lane], cu2 = su[128+lane];
  __syncthreads();                         // scratch reads done before state writes

  float4 Q[8];
  unsigned addr[16];

  // ---- pass 0: state |0..0> built directly in registers ----
  {
    #pragma unroll
    for (int k=0;k<8;++k) Q[k] = make_float4(0.f,0.f,0.f,0.f);
    if (t==0) Q[0].x = 1.0f;               // x=0: rep(0)=0, C[0][0]=0
    const unsigned cur = cu0; const int pl = 0;
    GATE(cT4.M[0][0],0); GATE(cT4.M[0][1],1); GATE(cT4.M[0][2],2); GATE(cT4.M[0][3],3);
    unsigned rep = 0;
    #pragma unroll
    for (int i=0;i<8;++i) rep ^= (((unsigned)t>>i)&1u) ? cT4.B[0][i] : 0u;
    #pragma unroll
    for (int z=0;z<16;++z) s2[rep ^ cT4.C[0][z]] = make_float2(SR(z), SI(z));
  }
  // NO barrier: pass 1 reads this wave's own writes (pair 0,1)

  // ---- passes 1..11: read coset, 4 gates, write back in place ----
  #pragma unroll 1
  for (int p=1; p<12; ++p){
    unsigned rep = 0;
    #pragma unroll
    for (int i=0;i<8;++i) rep ^= (((unsigned)t>>i)&1u) ? cT4.B[p][i] : 0u;
    #pragma unroll
    for (int z=0;z<16;++z) addr[z] = rep ^ cT4.C[p][z];
    #pragma unroll
    for (int z=0;z<16;++z){ float2 v2 = s2[addr[z]]; SR(z)=v2.x; SI(z)=v2.y; }

    const int ps = p>>2;
    const unsigned cur = (ps==0)?cu0:((ps==1)?cu1:cu2);
    const int pl = (p&3)<<4;
    GATE(cT4.M[p][0],0); GATE(cT4.M[p][1],1); GATE(cT4.M[p][2],2); GATE(cT4.M[p][3],3);

    if (p < 11){
      #pragma unroll
      for (int z=0;z<16;++z) s2[addr[z]] = make_float2(SR(z), SI(z));
      if (p & 1) __syncthreads();          // barrier only BETWEEN pairs (p=1,3,5,7,9)
    }
  }

  // ---- measurement: 16-pt WHT over z (signs are GF(2) characters) ----
  float H[16];
  #pragma unroll
  for (int z=0;z<16;++z) H[z] = fmaf(SR(z),SR(z), SI(z)*SI(z));
  #pragma unroll
  for (int st=1; st<16; st<<=1){
    #pragma unroll
    for (int z=0;z<16;++z){
      if (z & st) continue;
      float a0=H[z], a1=H[z|st];
      H[z]=a0+a1; H[z|st]=a0-a1;
    }
  }
  float acc[12];
  #pragma unroll
  for (int q=0;q<12;++q){
    const unsigned ls = ((unsigned)(__popc(cT4.mq[q] & (unsigned)t) & 1)) << 31;
    acc[q] = __uint_as_float(__float_as_uint(H[cT4.uq[q]]) ^ ls);
  }

  __syncthreads();                         // all pass-11 reads done -> LDS reusable
  const int wv = t >> 6;
  #pragma unroll
  for (int q=0;q<12;++q){
    float v = acc[q];
    #pragma unroll
    for (int off=32; off>0; off>>=1) v += __shfl_down(v, off, 64);
    if (lane==0) sf[wv*12+q] = v;
  }
  __syncthreads();
  if (t < 12) sf[64+t] = sf[t] + sf[12+t] + sf[24+t] + sf[36+t];
  __syncthreads();

  // ---- epilogue MLP on wave 0 (r3/r6-validated) ----
  if (t < 64){
    float a = b3[t];
    #pragma unroll
    for (int k=0;k<12;++k) a = fmaf(sf[64+k], W3[k*64+t], a);
    float h2 = tanhf(a);
    float p0 = h2*W4[2*t+0], p1 = h2*W4[2*t+1];
    #pragma unroll
    for (int off=32; off>0; off>>=1){ p0 += __shfl_down(p0,off,64); p1 += __shfl_down(p1,off,64); }
    if (t==0){ out[2*b+0]=p0+b4[0]; out[2*b+1]=p1+b4[1]; }
  }
}

extern "C" void kernel_launch(void* const* d_in, const int* in_sizes, int n_in,
                              void* d_out, int out_size, void* d_ws, size_t ws_size,
                              hipStream_t stream)
{
  const float* noise = (const float*)d_in[0];
  const float* W1 = (const float*)d_in[1];
  const float* b1 = (const float*)d_in[2];
  const float* W2 = (const float*)d_in[3];
  const float* b2 = (const float*)d_in[4];
  const float* W3 = (const float*)d_in[5];
  const float* b3 = (const float*)d_in[6];
  const float* W4 = (const float*)d_in[7];
  const float* b4 = (const float*)d_in[8];
  float* out = (float*)d_out;
  const int batch = in_sizes[0] / NQ;   // 4096
  qgen<<<batch, TPB, 0, stream>>>(noise, W1, b1, W2, b2, W3, b3, W4, b4, out);
}

// Round 8
// 236.748 us; speedup vs baseline: 1.0161x; 1.0161x over previous
//
#include <hip/hip_runtime.h>
#include <math.h>

#define NQ  12
#define TPB 256

// ================= compile-time GF(2) machinery =================
// Folded space (validated r1/r3/r6): gate q,layer l pairs x <-> x^v, role=parity(r&x),
// r_j.v_i = delta_ij. PAIRED passes (2m,2m+1) share lane basis B[0..7]:
//   pass p0: thread t slot z holds x = B t ^ C0[z]
//   transition to p1 is wave-internal: x = B (t^gamma(z)) ^ C1[zeta(z)]
//   -> ds_bpermute with 6-bit lane xor gx, slot relabel sz (constexpr).
// Boundary m (after pair m): layout elem = sigma(Tp x) where Tp = coords in
// frame [V[p1] | B], sigma(e)=e^(((e>>4)&7)<<1). Writes: 8 contiguous b128
// (float4 idx (t<<3)|(k^(t&7))). Pair m+1 basis B' picked through the
// boundary map so reads (b64) hit the 4-dword/bank floor.

struct GF12 { unsigned row[12]; };

constexpr GF12 gf_id(){ GF12 m{}; for(int i=0;i<12;i++) m.row[i]=1u<<i; return m; }
constexpr GF12 gf_mul(const GF12&A,const GF12&B){
  GF12 r{};
  for(int i=0;i<12;i++){ unsigned acc=0;
    for(int k=0;k<12;k++) if((A.row[i]>>k)&1u) acc ^= B.row[k];
    r.row[i]=acc; }
  return r;
}
constexpr unsigned gf_apply(const GF12&A, unsigned x){
  unsigned y=0;
  for(int i=0;i<12;i++) y |= (unsigned)(__builtin_popcount(A.row[i]&x)&1)<<i;
  return y;
}
constexpr GF12 gf_cnot(int q){ GF12 m=gf_id(); int c=11-q, t=11-((q+1)%12); m.row[t]^=(1u<<c); return m; }
constexpr GF12 gf_inv(const GF12&A){
  unsigned a[12], inv[12];
  for(int i=0;i<12;i++){ a[i]=A.row[i]; inv[i]=1u<<i; }
  for(int c=0;c<12;c++){
    int p=-1;
    for(int r2=c;r2<12;r2++) if((a[r2]>>c)&1u){p=r2;break;}
    if(p<0) continue;
    unsigned ta=a[c]; a[c]=a[p]; a[p]=ta;
    unsigned ti=inv[c]; inv[c]=inv[p]; inv[p]=ti;
    for(int r2=0;r2<12;r2++) if(r2!=c && ((a[r2]>>c)&1u)){ a[r2]^=a[c]; inv[r2]^=inv[c]; }
  }
  GF12 R{}; for(int i=0;i<12;i++) R.row[i]=inv[i];
  return R;
}

struct Red { unsigned arr[12]; int hb[12]; int n; };
constexpr unsigned red_reduce(const Red& R, unsigned y){
  for(int i=0;i<R.n;i++) if((y>>R.hb[i])&1u) y ^= R.arr[i];
  return y;
}
constexpr bool red_add(Red& R, unsigned cand){
  unsigned y = red_reduce(R, cand);
  if(!y) return false;
  int h=0;
  for(int b2=11;b2>=1;b2--) if((y>>b2)&1u){ h=b2; break; }
  R.arr[R.n]=y; R.hb[R.n]=h; R.n++;
  return true;
}

struct PairT {
  unsigned M0[4], M1[4];   // role masks (8-bit over t) for passes p0,p1
  unsigned sz[16], gx[16]; // bpermute: src slot, lane-xor (6-bit) per dest slot
  unsigned rB[8], roff[16];// read basis/offsets in prev-boundary elem space (m>0)
};
struct AllT { PairT pr[6]; unsigned mq[12], uq[12]; bool ok; };

constexpr AllT makeAll(){
  AllT T{}; T.ok=true;
  GF12 D=gf_id(); for(int q=0;q<12;q++) D=gf_mul(gf_cnot(q),D);
  GF12 Cm=gf_id(); for(int q=11;q>=0;q--) Cm=gf_mul(gf_cnot(q),Cm);
  unsigned V[12][4]{},R[12][4]{},rfin[12]{};
  GF12 Mm=gf_id(), Mi=gf_id();
  for(int l=0;l<4;l++){
    for(int q=0;q<12;q++){
      int b=11-q; unsigned v=0;
      for(int j=0;j<12;j++) v|=((Mi.row[j]>>b)&1u)<<j;
      V[l*3+q/4][q&3]=v; R[l*3+q/4][q&3]=Mm.row[b];
    }
    Mm=gf_mul(D,Mm); Mi=gf_mul(Cm,Mi);
  }
  for(int q=0;q<12;q++) rfin[q]=Mm.row[11-q];

  // sigma as GF12 (elem-space): bits 1..3 ^= bits 4..6; involution.
  GF12 Sg=gf_id(); Sg.row[1]|=1u<<4; Sg.row[2]|=1u<<5; Sg.row[3]|=1u<<6;

  GF12 Tprev{}, Tprev_inv{};          // boundary maps (valid from m>=1 iteration)
  for(int m=0;m<6;m++){
    const int p0=2*m, p1=p0+1;
    for(int pp=p0;pp<=p1;pp++) for(int j=0;j<4;j++) for(int i=0;i<4;i++){
      int par=__builtin_popcount(R[pp][j]&V[pp][i])&1;
      if(par!=((i==j)?1:0)) T.ok=false;
    }
    // S: 10-dim containing V[p0]+V[p1]
    Red S{};
    for(int i=0;i<4;i++){ red_add(S,V[p0][i]); red_add(S,V[p1][i]); }
    for(unsigned x=1;x<4096 && S.n<10;x++) red_add(S,x);
    if(S.n!=10) T.ok=false;
    Red S12=S, RA{}, RB{};
    for(int i=0;i<4;i++){ red_add(RA,V[p0][i]); red_add(RB,V[p1][i]); }
    unsigned B[8]{};
    Red resR{};                        // picked residues (4-bit space)
    for(int k=0;k<6;k++){
      unsigned pick=0;
      if(m>0){
        // tier 1: planned residue (1<<k for k<4, 0 for k>=4), exhaustive preimage
        unsigned res=(k<4)?(1u<<k):0u;
        for(unsigned hi=(k<4)?0u:1u; hi<256 && !pick; hi++){
          unsigned y=res|(hi<<4);
          unsigned x=gf_apply(Tprev_inv,y);
          if(red_reduce(S,x)) continue;
          if(!red_reduce(RA,x)) continue;
          if(!red_reduce(RB,x)) continue;
          pick=x;
        }
        // tier 2: any y; k<4 requires residue independent of picked residues
        for(unsigned y=1;y<4096 && !pick;y++){
          unsigned x=gf_apply(Tprev_inv,y);
          if(red_reduce(S,x)) continue;
          if(!red_reduce(RA,x)) continue;
          if(!red_reduce(RB,x)) continue;
          if(k<4){ unsigned rb=y&15u; if(!rb || !red_reduce(resR,rb)) continue; }
          pick=x;
        }
      }
      if(!pick){  // m==0 (no read constraints) or last resort
        for(unsigned x=1;x<4096 && !pick;x++){
          if(red_reduce(S,x)) continue;
          if(!red_reduce(RA,x)) continue;
          if(!red_reduce(RB,x)) continue;
          pick=x;
        }
      }
      if(!pick){ T.ok=false; pick=1; }
      if(m>0 && k<4){ unsigned rb=gf_apply(Tprev,pick)&15u; if(rb) red_add(resR,rb); }
      red_add(RA,pick); red_add(RB,pick);
      B[k]=pick;
    }
    for(int k=6;k<8;k++){
      unsigned pick=0;
      for(unsigned x=1;x<4096 && !pick;x++) if(red_reduce(S12,x)) pick=x;
      if(!pick){ T.ok=false; pick=1; }
      red_add(S12,pick); B[k]=pick;
    }
    if(S12.n!=12) T.ok=false;
    // frame Z (coords->x), Tp (x->coords)
    GF12 Z{};
    for(int i=0;i<12;i++){
      unsigned rr=0;
      for(int k=0;k<4;k++) rr |= ((V[p1][k]>>i)&1u)<<k;
      for(int k=0;k<8;k++) rr |= ((B[k]>>i)&1u)<<(4+k);
      Z.row[i]=rr;
    }
    GF12 Tp=gf_inv(Z);
    { GF12 I2=gf_mul(Tp,Z); for(int i=0;i<12;i++) if(I2.row[i]!=(1u<<i)) T.ok=false; }
    // role masks
    for(int j=0;j<4;j++){
      unsigned m0=0,m1=0;
      for(int k=0;k<8;k++){
        m0 |= (unsigned)(__builtin_popcount(R[p0][j]&B[k])&1)<<k;
        m1 |= (unsigned)(__builtin_popcount(R[p1][j]&B[k])&1)<<k;
      }
      T.pr[m].M0[j]=m0; T.pr[m].M1[j]=m1;
    }
    // bpermute decomposition: V[p0][i] over [V[p1]|B]; no B6/B7 component
    unsigned zeta[4]{}, gam[4]{};
    for(int i=0;i<4;i++){
      unsigned d=gf_apply(Tp,V[p0][i]);
      if(d>>10) T.ok=false;
      zeta[i]=d&15u; gam[i]=(d>>4)&63u;
    }
    unsigned zmap[16]{}; bool seen[16]{};
    for(int z=0;z<16;z++){
      unsigned zz=0;
      for(int i=0;i<4;i++) if((z>>i)&1) zz^=zeta[i];
      zmap[z]=zz;
      if(seen[zz]) T.ok=false; seen[zz]=true;
    }
    for(int zp=0;zp<16;zp++){
      unsigned src=0;
      for(int z=0;z<16;z++) if(zmap[z]==(unsigned)zp) src=(unsigned)z;
      unsigned gg=0;
      for(int i=0;i<4;i++) if((src>>i)&1) gg^=gam[i];
      T.pr[m].sz[zp]=src; T.pr[m].gx[zp]=gg;
    }
    // end-to-end pair invariant: C0[z] == C1[zmap[z]] ^ B*gamma(z)
    for(int z=0;z<16;z++){
      unsigned c0=0,c1=0,gg=0,bb=0;
      for(int i=0;i<4;i++){
        if((z>>i)&1){ c0^=V[p0][i]; gg^=gam[i]; }
        if((zmap[z]>>i)&1) c1^=V[p1][i];
      }
      for(int k=0;k<6;k++) if((gg>>k)&1) bb^=B[k];
      if((c0^c1^bb)!=0) T.ok=false;
    }
    // read tables for this pair (from prev boundary), m>0
    if(m>0){
      for(int k=0;k<8;k++) T.pr[m].rB[k]=gf_apply(Tprev,B[k]);
      for(int z=0;z<16;z++){
        unsigned c=0;
        for(int i=0;i<4;i++) if((z>>i)&1) c^=V[p0][i];
        T.pr[m].roff[z]=gf_apply(Tprev,c);
      }
    }
    // boundary map for next pair
    GF12 Tnew=gf_mul(Sg,Tp), Tnew_inv=gf_mul(Z,Sg);
    { GF12 I2=gf_mul(Tnew,Tnew_inv); for(int i=0;i<12;i++) if(I2.row[i]!=(1u<<i)) T.ok=false; }
    Tprev=Tnew; Tprev_inv=Tnew_inv;
    if(m==5){
      for(int q=0;q<12;q++){
        unsigned u=0,mm=0;
        for(int i=0;i<4;i++) u |= (unsigned)(__builtin_popcount(rfin[q]&V[11][i])&1)<<i;
        for(int k=0;k<8;k++) mm |= (unsigned)(__builtin_popcount(rfin[q]&B[k])&1)<<k;
        T.uq[q]=u; T.mq[q]=mm;
      }
    }
  }
  return T;
}

constexpr AllT hA = makeAll();
static_assert(hA.ok, "GF(2) paired-bpermute table self-check failed");

// register slot macros (param must NOT be named x/y/z/w — r2 lesson)
#define SR(n_) (((n_)&1) ? Q[(n_)>>1].z : Q[(n_)>>1].x)
#define SI(n_) (((n_)&1) ? Q[(n_)>>1].w : Q[(n_)>>1].y)
#define NR(n_) (((n_)&1) ? Qn[(n_)>>1].z : Qn[(n_)>>1].x)
#define NI(n_) (((n_)&1) ? Qn[(n_)>>1].w : Qn[(n_)>>1].y)

// butterfly with per-lane sign folded into ai/br (validated r1/r6)
#define GATE_BODY(RD,ID,MM,JJ) do { \
    const int _lb = pl + 4*(JJ); \
    const unsigned _sg = ((unsigned)(__popc((MM) & (unsigned)t) & 1)) << 31; \
    const float ar = __uint_as_float((unsigned)__builtin_amdgcn_readlane((int)cur, _lb+0)); \
    const float ai = __uint_as_float(((unsigned)__builtin_amdgcn_readlane((int)cur, _lb+1)) ^ _sg); \
    const float br = __uint_as_float(((unsigned)__builtin_amdgcn_readlane((int)cur, _lb+2)) ^ _sg); \
    const float bi = __uint_as_float((unsigned)__builtin_amdgcn_readlane((int)cur, _lb+3)); \
    _Pragma("unroll") \
    for (int s0=0; s0<16; ++s0){ \
      if ((s0 >> (JJ)) & 1) continue; \
      const int s1 = s0 | (1<<(JJ)); \
      const float xr=RD(s0), xi=ID(s0), yr=RD(s1), yi=ID(s1); \
      RD(s0)=fmaf(ar,xr,fmaf(-ai,xi,fmaf(br,yr,-(bi*yi)))); \
      ID(s0)=fmaf(ar,xi,fmaf( ai,xr,fmaf(br,yi,  bi*yr ))); \
      RD(s1)=fmaf(ar,yr,fmaf( ai,yi,fmaf(-br,xr,-(bi*xi)))); \
      ID(s1)=fmaf(ar,yi,fmaf(-ai,yr,fmaf( bi,xr,-(br*xi)))); \
    } \
  } while(0)
#define GATEQ(MM,JJ) GATE_BODY(SR,SI,MM,JJ)
#define GATEN(MM,JJ) GATE_BODY(NR,NI,MM,JJ)

template<int M>
__device__ __forceinline__ void do_pair(float4 Q[8], float4 Qn[8],
                                        unsigned c0, unsigned c1, unsigned c2,
                                        unsigned t, float2* s2, float4* s4)
{
  constexpr PairT P = hA.pr[M];
  if constexpr (M > 0){
    unsigned base=0;
    #pragma unroll
    for(int k=0;k<8;++k) base ^= ((t>>k)&1u) ? P.rB[k] : 0u;
    #pragma unroll
    for(int z=0;z<16;++z){ float2 v=s2[base ^ P.roff[z]]; SR(z)=v.x; SI(z)=v.y; }
  }
  // pass p0 = 2M
  { constexpr int ci=(2*M)>>2;
    const unsigned cur=(ci==0)?c0:((ci==1)?c1:c2);
    const int pl=((2*M)&3)<<4;
    GATEQ(P.M0[0],0); GATEQ(P.M0[1],1); GATEQ(P.M0[2],2); GATEQ(P.M0[3],3); }
  // wave-internal transition: dest slot zp pulls (src slot sz) from lane t^gx
  { const unsigned t4=t<<2;
    #pragma unroll
    for(int zp=0; zp<16; ++zp){
      const int idx=(int)(t4 ^ (P.gx[zp]<<2));
      NR(zp)=__uint_as_float((unsigned)__builtin_amdgcn_ds_bpermute(idx,(int)__float_as_uint(SR(P.sz[zp]))));
      NI(zp)=__uint_as_float((unsigned)__builtin_amdgcn_ds_bpermute(idx,(int)__float_as_uint(SI(P.sz[zp]))));
    } }
  // pass p1 = 2M+1
  { constexpr int ci=(2*M+1)>>2;
    const unsigned cur=(ci==0)?c0:((ci==1)?c1:c2);
    const int pl=((2*M+1)&3)<<4;
    GATEN(P.M1[0],0); GATEN(P.M1[1],1); GATEN(P.M1[2],2); GATEN(P.M1[3],3); }
  if constexpr (M < 5){
    __syncthreads();                   // all waves' pair-M reads complete
    const unsigned wb=t<<3;
    #pragma unroll
    for(int k=0;k<8;++k) s4[wb | ((unsigned)k ^ (t&7u))] = Qn[k];  // b128 burst
    __syncthreads();                   // writes visible to pair M+1 reads
  }
}

__global__ void __launch_bounds__(TPB, 5)
qgen(const float* __restrict__ noise,
     const float* __restrict__ W1, const float* __restrict__ b1,
     const float* __restrict__ W2, const float* __restrict__ b2,
     const float* __restrict__ W3, const float* __restrict__ b3,
     const float* __restrict__ W4, const float* __restrict__ b4,
     float* __restrict__ out)
{
  __shared__ float2 s2[4096];          // 32 KiB -> 5 blocks/CU
  float*  sf=(float*)s2;
  float4* s4=(float4*)s2;

  const unsigned t = threadIdx.x;
  const int b = blockIdx.x;
  const int lane = t & 63;

  // ---- prologue MLP (r3/r6-validated; scratch aliased into state) ----
  if (t < 12) sf[400+t] = noise[b*12+t];
  __syncthreads();
  if (t < 64){
    float a = b1[t];
    #pragma unroll
    for (int k=0;k<12;++k) a = fmaf(sf[400+k], W1[k*64+t], a);
    sf[192+t] = tanhf(a);
  }
  __syncthreads();
  if (t < 144){
    float a = b2[t];
    #pragma unroll 16
    for (int j=0;j<64;++j) a = fmaf(sf[192+j], W2[j*144+t], a);
    sf[256+t] = a;
  }
  __syncthreads();
  if (t < 48){
    float aa = sf[256+3*t+0]*0.5f, bb = sf[256+3*t+1]*0.5f, c = sf[256+3*t+2]*0.5f;
    float sa,ca,sb,cb,sc2,cc;
    __sincosf(aa,&sa,&ca); __sincosf(bb,&sb,&cb); __sincosf(c,&sc2,&cc);
    float A=cb*ca, B=sb*sa, Cc=sb*ca, Dd=cb*sa;
    s4[t] = make_float4(fmaf(cc,A,  sc2*B),  fmaf(cc,B, -sc2*A),
                        fmaf(-cc,Cc,-sc2*Dd), fmaf(sc2,Cc,-cc*Dd));
  }
  __syncthreads();
  const unsigned* su=(const unsigned*)s2;
  const unsigned cu0=su[lane], cu1=su[64+lane], cu2=su[128+lane];
  __syncthreads();                     // scratch reads done before state writes

  // ---- state: |0..0> -> lane 0, slot 0 in every frame ----
  float4 Q[8], Qn[8];
  #pragma unroll
  for(int k=0;k<8;++k) Q[k]=make_float4(0.f,0.f,0.f,0.f);
  if(t==0) Q[0].x=1.0f;

  do_pair<0>(Q,Qn,cu0,cu1,cu2,t,s2,s4);
  do_pair<1>(Q,Qn,cu0,cu1,cu2,t,s2,s4);
  do_pair<2>(Q,Qn,cu0,cu1,cu2,t,s2,s4);
  do_pair<3>(Q,Qn,cu0,cu1,cu2,t,s2,s4);
  do_pair<4>(Q,Qn,cu0,cu1,cu2,t,s2,s4);
  do_pair<5>(Q,Qn,cu0,cu1,cu2,t,s2,s4);   // final state in Qn

  // ---- measurement: 16-pt WHT over z (r6-validated) ----
  float H[16];
  #pragma unroll
  for(int z=0;z<16;++z) H[z]=fmaf(NR(z),NR(z), NI(z)*NI(z));
  #pragma unroll
  for(int st=1;st<16;st<<=1){
    #pragma unroll
    for(int z=0;z<16;++z){
      if(z & st) continue;
      float a0=H[z], a1=H[z|st];
      H[z]=a0+a1; H[z|st]=a0-a1;
    }
  }
  float acc[12];
  #pragma unroll
  for(int q=0;q<12;++q){
    constexpr_pragma_dummy: ;
    const unsigned ls=((unsigned)(__popc(hA.mq[q]&t)&1))<<31;
    acc[q]=__uint_as_float(__float_as_uint(H[hA.uq[q]])^ls);
  }

  __syncthreads();                     // all pair-5 reads done -> LDS reusable
  const int wv=t>>6;
  #pragma unroll
  for(int q=0;q<12;++q){
    float v=acc[q];
    #pragma unroll
    for(int off=32;off>0;off>>=1) v += __shfl_down(v,off,64);
    if(lane==0) sf[wv*12+q]=v;
  }
  __syncthreads();
  if(t<12) sf[64+t]=sf[t]+sf[12+t]+sf[24+t]+sf[36+t];
  __syncthreads();

  // ---- epilogue MLP on wave 0 (r3/r6-validated) ----
  if(t<64){
    float a=b3[t];
    #pragma unroll
    for(int k=0;k<12;++k) a=fmaf(sf[64+k],W3[k*64+t],a);
    float h2=tanhf(a);
    float p0=h2*W4[2*t+0], p1=h2*W4[2*t+1];
    #pragma unroll
    for(int off=32;off>0;off>>=1){ p0+=__shfl_down(p0,off,64); p1+=__shfl_down(p1,off,64); }
    if(t==0){ out[2*b+0]=p0+b4[0]; out[2*b+1]=p1+b4[1]; }
  }
}

extern "C" void kernel_launch(void* const* d_in, const int* in_sizes, int n_in,
                              void* d_out, int out_size, void* d_ws, size_t ws_size,
                              hipStream_t stream)
{
  const float* noise=(const float*)d_in[0];
  const float* W1=(const float*)d_in[1];
  const float* b1=(const float*)d_in[2];
  const float* W2=(const float*)d_in[3];
  const float* b2=(const float*)d_in[4];
  const float* W3=(const float*)d_in[5];
  const float* b3=(const float*)d_in[6];
  const float* W4=(const float*)d_in[7];
  const float* b4=(const float*)d_in[8];
  float* out=(float*)d_out;
  const int batch=in_sizes[0]/NQ;   // 4096
  qgen<<<batch,TPB,0,stream>>>(noise,W1,b1,W2,b2,W3,b3,W4,b4,out);
}

// Round 9
// 200.409 us; speedup vs baseline: 1.2004x; 1.1813x over previous
//
#include <hip/hip_runtime.h>
#include <math.h>

#define NQ  12
#define TPB 256

typedef __attribute__((ext_vector_type(2))) float f2;

// ================= compile-time GF(2) machinery (r8-validated) =================
// Folded space: gate q,layer l pairs x <-> x^v, role=parity(r&x), r_j.v_i=delta_ij.
// PAIRED passes (2m,2m+1) share lane basis B[0..7]; intra-pair transition is a
// wave-internal ds_bpermute (slot relabel sz, lane-xor gx). Boundary m: layout
// elem = sigma(Tp x); writes 8 contiguous swizzled b128, next-pair reads 16
// conflict-floor b64 (residues engineered through the boundary map).

struct GF12 { unsigned row[12]; };

constexpr GF12 gf_id(){ GF12 m{}; for(int i=0;i<12;i++) m.row[i]=1u<<i; return m; }
constexpr GF12 gf_mul(const GF12&A,const GF12&B){
  GF12 r{};
  for(int i=0;i<12;i++){ unsigned acc=0;
    for(int k=0;k<12;k++) if((A.row[i]>>k)&1u) acc ^= B.row[k];
    r.row[i]=acc; }
  return r;
}
constexpr unsigned gf_apply(const GF12&A, unsigned x){
  unsigned y=0;
  for(int i=0;i<12;i++) y |= (unsigned)(__builtin_popcount(A.row[i]&x)&1)<<i;
  return y;
}
constexpr GF12 gf_cnot(int q){ GF12 m=gf_id(); int c=11-q, t=11-((q+1)%12); m.row[t]^=(1u<<c); return m; }
constexpr GF12 gf_inv(const GF12&A){
  unsigned a[12], inv[12];
  for(int i=0;i<12;i++){ a[i]=A.row[i]; inv[i]=1u<<i; }
  for(int c=0;c<12;c++){
    int p=-1;
    for(int r2=c;r2<12;r2++) if((a[r2]>>c)&1u){p=r2;break;}
    if(p<0) continue;
    unsigned ta=a[c]; a[c]=a[p]; a[p]=ta;
    unsigned ti=inv[c]; inv[c]=inv[p]; inv[p]=ti;
    for(int r2=0;r2<12;r2++) if(r2!=c && ((a[r2]>>c)&1u)){ a[r2]^=a[c]; inv[r2]^=inv[c]; }
  }
  GF12 R{}; for(int i=0;i<12;i++) R.row[i]=inv[i];
  return R;
}

struct Red { unsigned arr[12]; int hb[12]; int n; };
constexpr unsigned red_reduce(const Red& R, unsigned y){
  for(int i=0;i<R.n;i++) if((y>>R.hb[i])&1u) y ^= R.arr[i];
  return y;
}
constexpr bool red_add(Red& R, unsigned cand){
  unsigned y = red_reduce(R, cand);
  if(!y) return false;
  int h=0;
  for(int b2=11;b2>=1;b2--) if((y>>b2)&1u){ h=b2; break; }
  R.arr[R.n]=y; R.hb[R.n]=h; R.n++;
  return true;
}

struct PairT {
  unsigned M0[4], M1[4];
  unsigned sz[16], gx[16];
  unsigned rB[8], roff[16];
};
struct AllT { PairT pr[6]; unsigned mq[12], uq[12]; bool ok; };

constexpr AllT makeAll(){
  AllT T{}; T.ok=true;
  GF12 D=gf_id(); for(int q=0;q<12;q++) D=gf_mul(gf_cnot(q),D);
  GF12 Cm=gf_id(); for(int q=11;q>=0;q--) Cm=gf_mul(gf_cnot(q),Cm);
  unsigned V[12][4]{},R[12][4]{},rfin[12]{};
  GF12 Mm=gf_id(), Mi=gf_id();
  for(int l=0;l<4;l++){
    for(int q=0;q<12;q++){
      int b=11-q; unsigned v=0;
      for(int j=0;j<12;j++) v|=((Mi.row[j]>>b)&1u)<<j;
      V[l*3+q/4][q&3]=v; R[l*3+q/4][q&3]=Mm.row[b];
    }
    Mm=gf_mul(D,Mm); Mi=gf_mul(Cm,Mi);
  }
  for(int q=0;q<12;q++) rfin[q]=Mm.row[11-q];

  GF12 Sg=gf_id(); Sg.row[1]|=1u<<4; Sg.row[2]|=1u<<5; Sg.row[3]|=1u<<6;

  GF12 Tprev{}, Tprev_inv{};
  for(int m=0;m<6;m++){
    const int p0=2*m, p1=p0+1;
    for(int pp=p0;pp<=p1;pp++) for(int j=0;j<4;j++) for(int i=0;i<4;i++){
      int par=__builtin_popcount(R[pp][j]&V[pp][i])&1;
      if(par!=((i==j)?1:0)) T.ok=false;
    }
    Red S{};
    for(int i=0;i<4;i++){ red_add(S,V[p0][i]); red_add(S,V[p1][i]); }
    for(unsigned x=1;x<4096 && S.n<10;x++) red_add(S,x);
    if(S.n!=10) T.ok=false;
    Red S12=S, RA{}, RB{};
    for(int i=0;i<4;i++){ red_add(RA,V[p0][i]); red_add(RB,V[p1][i]); }
    unsigned B[8]{};
    Red resR{};
    for(int k=0;k<6;k++){
      unsigned pick=0;
      if(m>0){
        unsigned res=(k<4)?(1u<<k):0u;
        for(unsigned hi=(k<4)?0u:1u; hi<256 && !pick; hi++){
          unsigned y=res|(hi<<4);
          unsigned x=gf_apply(Tprev_inv,y);
          if(red_reduce(S,x)) continue;
          if(!red_reduce(RA,x)) continue;
          if(!red_reduce(RB,x)) continue;
          pick=x;
        }
        for(unsigned y=1;y<4096 && !pick;y++){
          unsigned x=gf_apply(Tprev_inv,y);
          if(red_reduce(S,x)) continue;
          if(!red_reduce(RA,x)) continue;
          if(!red_reduce(RB,x)) continue;
          if(k<4){ unsigned rb=y&15u; if(!rb || !red_reduce(resR,rb)) continue; }
          pick=x;
        }
      }
      if(!pick){
        for(unsigned x=1;x<4096 && !pick;x++){
          if(red_reduce(S,x)) continue;
          if(!red_reduce(RA,x)) continue;
          if(!red_reduce(RB,x)) continue;
          pick=x;
        }
      }
      if(!pick){ T.ok=false; pick=1; }
      if(m>0 && k<4){ unsigned rb=gf_apply(Tprev,pick)&15u; if(rb) red_add(resR,rb); }
      red_add(RA,pick); red_add(RB,pick);
      B[k]=pick;
    }
    for(int k=6;k<8;k++){
      unsigned pick=0;
      for(unsigned x=1;x<4096 && !pick;x++) if(red_reduce(S12,x)) pick=x;
      if(!pick){ T.ok=false; pick=1; }
      red_add(S12,pick); B[k]=pick;
    }
    if(S12.n!=12) T.ok=false;
    GF12 Z{};
    for(int i=0;i<12;i++){
      unsigned rr=0;
      for(int k=0;k<4;k++) rr |= ((V[p1][k]>>i)&1u)<<k;
      for(int k=0;k<8;k++) rr |= ((B[k]>>i)&1u)<<(4+k);
      Z.row[i]=rr;
    }
    GF12 Tp=gf_inv(Z);
    { GF12 I2=gf_mul(Tp,Z); for(int i=0;i<12;i++) if(I2.row[i]!=(1u<<i)) T.ok=false; }
    for(int j=0;j<4;j++){
      unsigned m0=0,m1=0;
      for(int k=0;k<8;k++){
        m0 |= (unsigned)(__builtin_popcount(R[p0][j]&B[k])&1)<<k;
        m1 |= (unsigned)(__builtin_popcount(R[p1][j]&B[k])&1)<<k;
      }
      T.pr[m].M0[j]=m0; T.pr[m].M1[j]=m1;
    }
    unsigned zeta[4]{}, gam[4]{};
    for(int i=0;i<4;i++){
      unsigned d=gf_apply(Tp,V[p0][i]);
      if(d>>10) T.ok=false;
      zeta[i]=d&15u; gam[i]=(d>>4)&63u;
    }
    unsigned zmap[16]{}; bool seen[16]{};
    for(int z=0;z<16;z++){
      unsigned zz=0;
      for(int i=0;i<4;i++) if((z>>i)&1) zz^=zeta[i];
      zmap[z]=zz;
      if(seen[zz]) T.ok=false; seen[zz]=true;
    }
    for(int zp=0;zp<16;zp++){
      unsigned src=0;
      for(int z=0;z<16;z++) if(zmap[z]==(unsigned)zp) src=(unsigned)z;
      unsigned gg=0;
      for(int i=0;i<4;i++) if((src>>i)&1) gg^=gam[i];
      T.pr[m].sz[zp]=src; T.pr[m].gx[zp]=gg;
    }
    for(int z=0;z<16;z++){
      unsigned c0=0,c1=0,gg=0,bb=0;
      for(int i=0;i<4;i++){
        if((z>>i)&1){ c0^=V[p0][i]; gg^=gam[i]; }
        if((zmap[z]>>i)&1) c1^=V[p1][i];
      }
      for(int k=0;k<6;k++) if((gg>>k)&1) bb^=B[k];
      if((c0^c1^bb)!=0) T.ok=false;
    }
    if(m>0){
      for(int k=0;k<8;k++) T.pr[m].rB[k]=gf_apply(Tprev,B[k]);
      for(int z=0;z<16;z++){
        unsigned c=0;
        for(int i=0;i<4;i++) if((z>>i)&1) c^=V[p0][i];
        T.pr[m].roff[z]=gf_apply(Tprev,c);
      }
    }
    GF12 Tnew=gf_mul(Sg,Tp), Tnew_inv=gf_mul(Z,Sg);
    { GF12 I2=gf_mul(Tnew,Tnew_inv); for(int i=0;i<12;i++) if(I2.row[i]!=(1u<<i)) T.ok=false; }
    Tprev=Tnew; Tprev_inv=Tnew_inv;
    if(m==5){
      for(int q=0;q<12;q++){
        unsigned u=0,mm=0;
        for(int i=0;i<4;i++) u |= (unsigned)(__builtin_popcount(rfin[q]&V[11][i])&1)<<i;
        for(int k=0;k<8;k++) mm |= (unsigned)(__builtin_popcount(rfin[q]&B[k])&1)<<k;
        T.uq[q]=u; T.mq[q]=mm;
      }
    }
  }
  return T;
}

constexpr AllT hA = makeAll();
static_assert(hA.ok, "GF(2) paired-bpermute table self-check failed");

// ---- packed butterfly: 8 v_pk_fma_f32-class ops per (s0,s1) pair ----
// out0 = A0*X + A1*Xs + B0*Y + B1*Ys ; out1 = A0*Y - A1*Ys - B0*X + B1*Xs
// A0=(ar,ar) A1=(-ai',ai') B0=(br',br') B1=(-bi,bi); ai',br' carry role sign.
// Verified vs r1-validated scalar form term-by-term.
#define GATE_PK(SS,MM,JJ) do { \
    const int _lb = pl + 4*(JJ); \
    const unsigned _sg = ((unsigned)(__popc((MM) & (unsigned)t) & 1)) << 31; \
    const float _ar = __uint_as_float((unsigned)__builtin_amdgcn_readlane((int)cur, _lb+0)); \
    const float _ai = __uint_as_float(((unsigned)__builtin_amdgcn_readlane((int)cur, _lb+1)) ^ _sg); \
    const float _br = __uint_as_float(((unsigned)__builtin_amdgcn_readlane((int)cur, _lb+2)) ^ _sg); \
    const float _bi = __uint_as_float((unsigned)__builtin_amdgcn_readlane((int)cur, _lb+3)); \
    const f2 A0 = {_ar,_ar}, A1 = {-_ai,_ai}, B0 = {_br,_br}, B1 = {-_bi,_bi}; \
    _Pragma("unroll") \
    for (int s0=0; s0<16; ++s0){ \
      if ((s0 >> (JJ)) & 1) continue; \
      const int s1 = s0 | (1<<(JJ)); \
      const f2 X = SS[s0], Y = SS[s1]; \
      const f2 Xs = __builtin_shufflevector(X,X,1,0); \
      const f2 Ys = __builtin_shufflevector(Y,Y,1,0); \
      SS[s0] = __builtin_elementwise_fma(A0,X, \
               __builtin_elementwise_fma(A1,Xs, \
               __builtin_elementwise_fma(B0,Y, B1*Ys))); \
      SS[s1] = __builtin_elementwise_fma(A0,Y, \
               __builtin_elementwise_fma(-A1,Ys, \
               __builtin_elementwise_fma(-B0,X, B1*Xs))); \
    } \
  } while(0)

template<int M>
__device__ __forceinline__ void do_pair(f2 S[16], f2 Sn[16],
                                        unsigned c0, unsigned c1, unsigned c2,
                                        unsigned t, float2* s2, float4* s4)
{
  constexpr PairT P = hA.pr[M];
  if constexpr (M > 0){
    unsigned base=0;
    #pragma unroll
    for(int k=0;k<8;++k) base ^= ((t>>k)&1u) ? P.rB[k] : 0u;
    #pragma unroll
    for(int z=0;z<16;++z){ float2 v=s2[base ^ P.roff[z]]; S[z].x=v.x; S[z].y=v.y; }
  }
  // pass p0 = 2M
  { constexpr int ci=(2*M)>>2;
    const unsigned cur=(ci==0)?c0:((ci==1)?c1:c2);
    const int pl=((2*M)&3)<<4;
    GATE_PK(S,P.M0[0],0); GATE_PK(S,P.M0[1],1); GATE_PK(S,P.M0[2],2); GATE_PK(S,P.M0[3],3); }
  // wave-internal transition (r8-validated): dest zp pulls src slot sz from lane t^gx
  { const unsigned t4=t<<2;
    #pragma unroll
    for(int zp=0; zp<16; ++zp){
      const int idx=(int)(t4 ^ (P.gx[zp]<<2));
      Sn[zp].x=__uint_as_float((unsigned)__builtin_amdgcn_ds_bpermute(idx,(int)__float_as_uint(S[P.sz[zp]].x)));
      Sn[zp].y=__uint_as_float((unsigned)__builtin_amdgcn_ds_bpermute(idx,(int)__float_as_uint(S[P.sz[zp]].y)));
    } }
  // pass p1 = 2M+1
  { constexpr int ci=(2*M+1)>>2;
    const unsigned cur=(ci==0)?c0:((ci==1)?c1:c2);
    const int pl=((2*M+1)&3)<<4;
    GATE_PK(Sn,P.M1[0],0); GATE_PK(Sn,P.M1[1],1); GATE_PK(Sn,P.M1[2],2); GATE_PK(Sn,P.M1[3],3); }
  if constexpr (M < 5){
    __syncthreads();
    const unsigned wb=t<<3;
    #pragma unroll
    for(int k=0;k<8;++k)
      s4[wb | ((unsigned)k ^ (t&7u))] =
        make_float4(Sn[2*k].x, Sn[2*k].y, Sn[2*k+1].x, Sn[2*k+1].y);   // b128 burst
    __syncthreads();
  }
}

__global__ void __launch_bounds__(TPB, 5)
qgen(const float* __restrict__ noise,
     const float* __restrict__ W1, const float* __restrict__ b1,
     const float* __restrict__ W2, const float* __restrict__ b2,
     const float* __restrict__ W3, const float* __restrict__ b3,
     const float* __restrict__ W4, const float* __restrict__ b4,
     float* __restrict__ out)
{
  __shared__ float2 s2[4096];          // 32 KiB -> 5 blocks/CU
  float*  sf=(float*)s2;
  float4* s4=(float4*)s2;

  const unsigned t = threadIdx.x;
  const int b = blockIdx.x;
  const int lane = t & 63;

  // ---- prologue MLP (r3/r6-validated; scratch aliased into state) ----
  if (t < 12) sf[400+t] = noise[b*12+t];
  __syncthreads();
  if (t < 64){
    float a = b1[t];
    #pragma unroll
    for (int k=0;k<12;++k) a = fmaf(sf[400+k], W1[k*64+t], a);
    sf[192+t] = tanhf(a);
  }
  __syncthreads();
  if (t < 144){
    float a = b2[t];
    #pragma unroll 16
    for (int j=0;j<64;++j) a = fmaf(sf[192+j], W2[j*144+t], a);
    sf[256+t] = a;
  }
  __syncthreads();
  if (t < 48){
    float aa = sf[256+3*t+0]*0.5f, bb = sf[256+3*t+1]*0.5f, c = sf[256+3*t+2]*0.5f;
    float sa,ca,sb,cb,sc2,cc;
    __sincosf(aa,&sa,&ca); __sincosf(bb,&sb,&cb); __sincosf(c,&sc2,&cc);
    float A=cb*ca, B=sb*sa, Cc=sb*ca, Dd=cb*sa;
    s4[t] = make_float4(fmaf(cc,A,  sc2*B),  fmaf(cc,B, -sc2*A),
                        fmaf(-cc,Cc,-sc2*Dd), fmaf(sc2,Cc,-cc*Dd));
  }
  __syncthreads();
  const unsigned* su=(const unsigned*)s2;
  const unsigned cu0=su[lane], cu1=su[64+lane], cu2=su[128+lane];
  __syncthreads();                     // scratch reads done before state writes

  // ---- state: |0..0> -> lane 0, slot 0 in every frame ----
  f2 S[16], Sn[16];
  #pragma unroll
  for(int k=0;k<16;++k){ S[k].x=0.f; S[k].y=0.f; }
  if(t==0) S[0].x=1.0f;

  do_pair<0>(S,Sn,cu0,cu1,cu2,t,s2,s4);
  do_pair<1>(S,Sn,cu0,cu1,cu2,t,s2,s4);
  do_pair<2>(S,Sn,cu0,cu1,cu2,t,s2,s4);
  do_pair<3>(S,Sn,cu0,cu1,cu2,t,s2,s4);
  do_pair<4>(S,Sn,cu0,cu1,cu2,t,s2,s4);
  do_pair<5>(S,Sn,cu0,cu1,cu2,t,s2,s4);   // final state in Sn

  // ---- measurement: 16-pt WHT over z (r6-validated) ----
  float H[16];
  #pragma unroll
  for(int z=0;z<16;++z) H[z]=fmaf(Sn[z].x,Sn[z].x, Sn[z].y*Sn[z].y);
  #pragma unroll
  for(int st=1;st<16;st<<=1){
    #pragma unroll
    for(int z=0;z<16;++z){
      if(z & st) continue;
      float a0=H[z], a1=H[z|st];
      H[z]=a0+a1; H[z|st]=a0-a1;
    }
  }
  float acc[12];
  #pragma unroll
  for(int q=0;q<12;++q){
    const unsigned ls=((unsigned)(__popc(hA.mq[q]&t)&1))<<31;
    acc[q]=__uint_as_float(__float_as_uint(H[hA.uq[q]])^ls);
  }

  __syncthreads();                     // all pair-5 reads done -> LDS reusable
  const int wv=t>>6;
  #pragma unroll
  for(int q=0;q<12;++q){
    float v=acc[q];
    #pragma unroll
    for(int off=32;off>0;off>>=1) v += __shfl_down(v,off,64);
    if(lane==0) sf[wv*12+q]=v;
  }
  __syncthreads();
  if(t<12) sf[64+t]=sf[t]+sf[12+t]+sf[24+t]+sf[36+t];
  __syncthreads();

  // ---- epilogue MLP on wave 0 (r3/r6-validated) ----
  if(t<64){
    float a=b3[t];
    #pragma unroll
    for(int k=0;k<12;++k) a=fmaf(sf[64+k],W3[k*64+t],a);
    float h2=tanhf(a);
    float p0=h2*W4[2*t+0], p1=h2*W4[2*t+1];
    #pragma unroll
    for(int off=32;off>0;off>>=1){ p0+=__shfl_down(p0,off,64); p1+=__shfl_down(p1,off,64); }
    if(t==0){ out[2*b+0]=p0+b4[0]; out[2*b+1]=p1+b4[1]; }
  }
}

extern "C" void kernel_launch(void* const* d_in, const int* in_sizes, int n_in,
                              void* d_out, int out_size, void* d_ws, size_t ws_size,
                              hipStream_t stream)
{
  const float* noise=(const float*)d_in[0];
  const float* W1=(const float*)d_in[1];
  const float* b1=(const float*)d_in[2];
  const float* W2=(const float*)d_in[3];
  const float* b2=(const float*)d_in[4];
  const float* W3=(const float*)d_in[5];
  const float* b3=(const float*)d_in[6];
  const float* W4=(const float*)d_in[7];
  const float* b4=(const float*)d_in[8];
  float* out=(float*)d_out;
  const int batch=in_sizes[0]/NQ;   // 4096
  qgen<<<batch,TPB,0,stream>>>(noise,W1,b1,W2,b2,W3,b3,W4,b4,out);
}